// Round 10
// baseline (147.718 us; speedup 1.0000x reference)
//
#include <hip/hip_runtime.h>
#include <hip/hip_bf16.h>

// DenseAttention — reassociated (6.44 GF vs 155 GF direct), bf16 MFMA.
// Round 10: delete the prep dispatch entirely (r9 showed tile tuning neutral;
// remaining controllables = dispatch count + ws round-trips). K-major f32
// sources are scatter-staged straight into fragment-major LDS with inline
// f32->bf16 (stage_km64 — math HW-verified in round 6); row-major sources use
// the vector stager. G/Wt zeroed by a 4MB memsetAsync.
//   memset: zero G+Wt (4 MB)
//   gram:  G[bq][f][h] += x_f . x_h       grid(16,8,8)=1024, split-K8, atomic
//          (A/B direct from f32 x: m=f contiguous -> stage_km64)
//   2a:    Tt[ba][g][qf] = comb_g . G_f   grid(16,32)=512
//          (A direct from f32 comb: m=g contiguous -> stage_km64; B=G stage64)
//   2b:    Wt[ba][g][e] += Tt_g . qw_e    grid(16,8,4)=512, split-K4, atomic
//   out:   out[t][ag]   = x_t . Wt_g      grid(128,8)=1024
// All stores/atomics coalesced; fragment-major LDS -> conflict-free
// ds_read_b128 fragment reads (scatter WRITES are 8-way aliased — bounded).
// ws (12 MB): G 2 | Wt 2 | Tt 8.

typedef unsigned short u16;
using short8  = __attribute__((ext_vector_type(8))) short;
using floatx4 = __attribute__((ext_vector_type(4))) float;

__device__ inline u16 f2bf(float f) {               // RNE f32->bf16
    unsigned u = __float_as_uint(f);
    unsigned r = u + 0x7fffu + ((u >> 16) & 1u);
    return (u16)(r >> 16);
}

// Row-major source [64 m][64 k] (k-contiguous) -> fragment-major LDS (MT=4).
// Element (m,k): lane=((k&31)>>3)*16+(m&15), j=k&7,
// chunk=((k>>5)*4+(m>>4))*64+lane.
template <typename T>
__device__ inline void stage64(const T* __restrict__ src, long ld,
                               u16* __restrict__ dst, int tid) {
#pragma unroll
    for (int it = 0; it < 4; ++it) {
        const int flat = (it * 256 + tid) * 4;
        const int kl = flat & 63, rl = flat >> 6;
        ushort4 v;
        if (sizeof(T) == 4) {
            const float4 f = *(const float4*)&((const float*)src)[(long)rl * ld + kl];
            v.x = f2bf(f.x); v.y = f2bf(f.y); v.z = f2bf(f.z); v.w = f2bf(f.w);
        } else {
            v = *(const ushort4*)&((const u16*)src)[(long)rl * ld + kl];
        }
        const int chunk = ((kl >> 5) * 4 + (rl >> 4)) * 64 + ((kl >> 3) & 3) * 16 + (rl & 15);
        *(ushort4*)&dst[chunk * 8 + (kl & 7)] = v;
    }
}

// K-major f32 source [64 k][64 m] (m-contiguous, row stride ld) -> fragment-
// major LDS (MT=4), scatter writes. For (m+e,k), e=0..3: m%4==0 so (m+e)>>4
// == m>>4 and lane increments by e -> chunk = cb_+e (round-6-verified pattern).
__device__ inline void stage_km64(const float* __restrict__ src, long ld,
                                  u16* __restrict__ dst, int tid) {
#pragma unroll
    for (int it = 0; it < 4; ++it) {
        const int flat = (it * 256 + tid) * 4;
        const int m = flat & 63, k = flat >> 6;
        const float4 f = *(const float4*)&src[(long)k * ld + m];
        const int cb_ = ((k >> 5) * 4 + (m >> 4)) * 64 + ((k & 31) >> 3) * 16 + (m & 15);
        const int j = k & 7;
        dst[(cb_ + 0) * 8 + j] = f2bf(f.x);
        dst[(cb_ + 1) * 8 + j] = f2bf(f.y);
        dst[(cb_ + 2) * 8 + j] = f2bf(f.z);
        dst[(cb_ + 3) * 8 + j] = f2bf(f.w);
    }
}

// C[m0+..64, n0+..64] (+)= A . B^T. 4 waves, wave w -> 32x32 at
// (IA=(w&1)*2, JB=(w>>1)*2) 16-tiles. AKM/BKM: operand staged from K-major
// f32 (pass src at [k0-origin row][m-origin]).
template <typename TA, typename TB, bool AKM, bool BKM, bool ATOMIC>
__device__ inline void gemm_tile(const TA* __restrict__ A, long lda,
                                 const TB* __restrict__ B, long ldb,
                                 float* __restrict__ C, long ldc,
                                 int K, int m0, int n0) {
    __shared__ u16 As[4096];   // 8 KB
    __shared__ u16 Bs[4096];
    const int tid = threadIdx.x, lane = tid & 63, w = tid >> 6;
    const int IA = (w & 1) * 2, JB = (w >> 1) * 2;
    floatx4 acc[2][2] = {};

    for (int k0 = 0; k0 < K; k0 += 64) {
        if (AKM) stage_km64((const float*)A + (long)k0 * lda, lda, As, tid);
        else     stage64(A + k0, lda, As, tid);
        if (BKM) stage_km64((const float*)B + (long)k0 * ldb, ldb, Bs, tid);
        else     stage64(B + k0, ldb, Bs, tid);
        __syncthreads();
#pragma unroll
        for (int s = 0; s < 2; ++s) {
            short8 af[2], bfr[2];
#pragma unroll
            for (int i = 0; i < 2; ++i)
                af[i] = *(const short8*)&As[((s * 4 + IA + i) * 64 + lane) * 8];
#pragma unroll
            for (int j = 0; j < 2; ++j)
                bfr[j] = *(const short8*)&Bs[((s * 4 + JB + j) * 64 + lane) * 8];
#pragma unroll
            for (int i = 0; i < 2; ++i)
#pragma unroll
                for (int j = 0; j < 2; ++j)
                    acc[i][j] = __builtin_amdgcn_mfma_f32_16x16x32_bf16(af[i], bfr[j], acc[i][j], 0, 0, 0);
        }
        __syncthreads();
    }
    const int rb = (lane >> 4) * 4, col = lane & 15;
#pragma unroll
    for (int i = 0; i < 2; ++i)
#pragma unroll
        for (int j = 0; j < 2; ++j)
#pragma unroll
            for (int r = 0; r < 4; ++r) {
                const int gm = m0 + (IA + i) * 16 + rb + r;
                const int gn = n0 + (JB + j) * 16 + col;
                float* p = &C[(long)gm * ldc + gn];
                if (ATOMIC) atomicAdd(p, acc[i][j][r]); else *p = acc[i][j][r];
            }
}

// gram: G[bq][f][h] += sum_{u in split} x[b][u][qf] * x[b][u][qh]
// A[m=f][k=u]: src x rows (m contiguous), ld=1024 -> stage_km64.
__global__ __launch_bounds__(256) void k_gram(const float* __restrict__ x,
                                              float* __restrict__ G) {
    const int tile = blockIdx.x, bq = blockIdx.y, split = blockIdx.z;
    const int tm = tile >> 2, tn = tile & 3;
    const int b = bq >> 2, q = bq & 3;
    const float* base = x + (long)b * 2097152 + (long)split * 256 * 1024 + q * 256;
    gemm_tile<float, float, true, true, true>(
        base + tm * 64, 1024,
        base + tn * 64, 1024,
        G + (long)bq * 65536, 256,
        256, tm * 64, tn * 64);
}

// 2a: Tt[ba][g][q*256+f] = sum_h comb[a][q*256+h][g] * G[bq][f][h]
// A[m=g][k=h]: src comb rows (m=g contiguous), ld=256 -> stage_km64.
__global__ __launch_bounds__(256) void k_2a(const float* __restrict__ comb,
                                            const float* __restrict__ G,
                                            float* __restrict__ Tt) {
    const int tile = blockIdx.x, i = blockIdx.y;     // i = ba*4+q
    const int tm = tile >> 2, tn = tile & 3;
    const int q = i & 3, ba = i >> 2, b = ba >> 2, a = ba & 3;
    gemm_tile<float, float, true, false, false>(
        comb + (long)a * 262144 + (long)q * 256 * 256 + tm * 64, 256,
        G + (long)(b * 4 + q) * 65536 + (long)tn * 64 * 256, 256,
        Tt + (long)ba * 262144, 1024,
        256, tm * 64, q * 256 + tn * 64);
}

// 2b: Wt[ba][g][e] += sum_{k in split} Tt[ba][g][k] * qw[a][e][k]
__global__ __launch_bounds__(256) void k_2b(const float* __restrict__ Tt,
                                            const float* __restrict__ qw,
                                            float* __restrict__ Wt) {
    const int tile = blockIdx.x, ba = blockIdx.y, split = blockIdx.z;
    const int tm = tile >> 2, tn = tile & 3;
    const int a = ba & 3;
    gemm_tile<float, float, false, false, true>(
        Tt + (long)ba * 262144 + (long)tm * 64 * 1024 + split * 256, 1024,
        qw + (long)a * 262144 + (long)tn * 64 * 1024 + split * 256, 1024,
        Wt + (long)ba * 65536, 256,
        256, tm * 64, tn * 64);
}

// out: out[b][t][a*256+g] = sum_e x[b][t][a*256+e] * Wt[ba][g][e]
__global__ __launch_bounds__(256) void k_3(const float* __restrict__ x,
                                           const float* __restrict__ Wt,
                                           float* __restrict__ out) {
    const int tl = blockIdx.x, ba = blockIdx.y;      // tl: tm 0..31, tn 0..3
    const int tm = tl >> 2, tn = tl & 3;
    const int b = ba >> 2, a = ba & 3;
    gemm_tile<float, float, false, false, false>(
        x + (long)b * 2097152 + (long)tm * 64 * 1024 + a * 256, 1024,
        Wt + (long)ba * 65536 + (long)tn * 64 * 256, 256,
        out + (long)b * 2097152 + a * 256, 1024,
        256, tm * 64, tn * 64);
}

extern "C" void kernel_launch(void* const* d_in, const int* in_sizes, int n_in,
                              void* d_out, int out_size, void* d_ws, size_t ws_size,
                              hipStream_t stream) {
    const float* x    = (const float*)d_in[0];   // [2,2048,1024]
    const float* qw   = (const float*)d_in[1];   // [4,256,1024]
    const float* comb = (const float*)d_in[2];   // [4,1024,256]
    float* out = (float*)d_out;

    char* ws = (char*)d_ws;
    float* G  = (float*)(ws);                    // 2 MB [8][256x256] (G,Wt contiguous for memset)
    float* Wt = (float*)(ws + (2u << 20));       // 2 MB [8][256][256]  Wt[g][e]
    float* Tt = (float*)(ws + (4u << 20));       // 8 MB [8][256][1024] Tt[g][qf]

    hipMemsetAsync(d_ws, 0, 4u << 20, stream);   // zero G + Wt
    k_gram<<<dim3(16, 8, 8), 256, 0, stream>>>(x, G);
    k_2a  <<<dim3(16, 32),   256, 0, stream>>>(comb, G, Tt);
    k_2b  <<<dim3(16, 8, 4), 256, 0, stream>>>(Tt, qw, Wt);
    k_3   <<<dim3(128, 8),   256, 0, stream>>>(x, Wt, out);
}